// Round 9
// baseline (236.488 us; speedup 1.0000x reference)
//
#include <hip/hip_runtime.h>
#include <cstdint>
#include <cstddef>

typedef __attribute__((ext_vector_type(4))) float fvec4;
typedef __attribute__((ext_vector_type(8))) short bf8;            // 8 bf16 = 4 VGPR MFMA frag
typedef __attribute__((ext_vector_type(8))) unsigned short usvec8;
typedef __attribute__((ext_vector_type(4))) unsigned int uvec4;
typedef __attribute__((ext_vector_type(4))) float f32x4;

#define NNODES 100000
#define NEDGES 1600000
#define INDIM  128
#define HC     128
#define NH     8
#define LEAKY  0.2f
#define SM_EPS 1e-16f
#define NPART  98    // ceil(100000/1024) for row_start scan
#define BM     64    // nodes per block in k_gemm
#define GEMM_BLOCKS ((NNODES + BM - 1) / BM)   // 1563
#define WROWS  272   // 256 W cols + 8 wa_l + 8 wa_r
#define NBUCK  196   // scatter buckets (512 nodes each; dst>>9)
#define NPB_S  512   // nodes per scatter bucket
#define CHUNK  4096  // edges per partition block
#define CBLK   ((NEDGES + CHUNK - 1) / CHUNK)  // 391

__device__ __forceinline__ unsigned short f2bf_rne(float f) {
    uint32_t u = __builtin_bit_cast(uint32_t, f);
    u += 0x7FFFu + ((u >> 16) & 1u);
    return (unsigned short)(u >> 16);
}
__device__ __forceinline__ float bf2f(uint32_t lo16) {
    return __builtin_bit_cast(float, lo16 << 16);
}

// ---------------------------------------------------------------------------
// k_wt: build wt_g (bf16):
//   rows 0..255:  W_lin|W_res transposed [n][k], pre-swizzled 16B slots (^= n&7)
//   rows 256..263: wa_l[k,hd]; rows 264..271: wa_r (att folded into W_lin).
// ---------------------------------------------------------------------------
__global__ __launch_bounds__(256) void k_wt(
    const float* __restrict__ W_lin,
    const float* __restrict__ W_res,
    const float* __restrict__ att_l,
    const float* __restrict__ att_r,
    unsigned short* __restrict__ wt_g)
{
    const int idx = blockIdx.x * 256 + threadIdx.x;   // 0..4351
    if (idx >= WROWS * 16) return;
    const int n  = idx >> 4;                          // 0..271
    const int k8 = idx & 15;
    usvec8 o;
    if (n < 256) {
        const float* src = (n < 128) ? W_lin : W_res;
        const int col = n & 127;
        #pragma unroll
        for (int j = 0; j < 8; ++j)
            o[j] = f2bf_rne(src[(size_t)(k8 * 8 + j) * HC + col]);
        const int sw = k8 ^ (n & 7);
        *(usvec8*)&wt_g[(size_t)n * INDIM + sw * 8] = o;
    } else {
        const int hd = (n - 256) & 7;
        const float* att = (n < 264) ? att_l : att_r;
        #pragma unroll
        for (int j = 0; j < 8; ++j) {
            const int k = k8 * 8 + j;
            float s = 0.f;
            #pragma unroll
            for (int c = 0; c < 16; ++c)
                s += W_lin[(size_t)k * HC + 16 * hd + c] * att[16 * hd + c];
            o[j] = f2bf_rne(s);
        }
        *(usvec8*)&wt_g[(size_t)n * INDIM + k8 * 8] = o;
    }
}

// ---------------------------------------------------------------------------
// k_gemm (MFMA): per block 64 nodes x 272 cols (h | resid | alphas), K=128.
// LDS: wt 64KB + xs 16KB = 80KB -> 2 blocks/CU. Fused dst-degree histogram.
// ---------------------------------------------------------------------------
__global__ __launch_bounds__(256) void k_gemm(
    const float* __restrict__ x,
    const unsigned short* __restrict__ wt_g,
    const int*   __restrict__ ei,
    unsigned short* __restrict__ h16,
    unsigned short* __restrict__ resid16,
    float* __restrict__ alpha_l,
    float* __restrict__ alpha_r,
    int* __restrict__ deg)
{
    __shared__ unsigned short wt[256 * INDIM];  // 64 KB
    __shared__ unsigned short xs[BM * INDIM];   // 16 KB

    const int tid = threadIdx.x;
    const size_t nbase = (size_t)blockIdx.x * BM;

    // fused histogram: 1563*256*4 >= 1.6M  (16 atomics/address -> short chains)
    #pragma unroll
    for (int i = 0; i < 4; ++i) {
        const int e = blockIdx.x * 256 + tid + i * (GEMM_BLOCKS * 256);
        if (e < NEDGES) atomicAdd(&deg[ei[NEDGES + e]], 1);
    }

    // stage wt rows 0..255 (linear copy of pre-swizzled bf16)
    {
        const fvec4* s = (const fvec4*)wt_g;
        fvec4* d = (fvec4*)wt;
        #pragma unroll
        for (int i = 0; i < 16; ++i) d[tid + 256 * i] = s[tid + 256 * i];
    }
    // stage xs: thread = (row r0, quarter kq); f32->bf16, swizzled store
    {
        const int r0 = tid >> 2;
        const int kq = (tid & 3) * 32;
        const bool valid = (nbase + r0) < NNODES;
        const float* xr = x + (nbase + r0) * INDIM + kq;
        #pragma unroll
        for (int j2 = 0; j2 < 4; ++j2) {
            usvec8 o;
            if (valid) {
                fvec4 p0 = *(const fvec4*)(xr + j2 * 8);
                fvec4 p1 = *(const fvec4*)(xr + j2 * 8 + 4);
                #pragma unroll
                for (int j = 0; j < 4; ++j) { o[j] = f2bf_rne(p0[j]); o[4 + j] = f2bf_rne(p1[j]); }
            } else {
                #pragma unroll
                for (int j = 0; j < 8; ++j) o[j] = 0;
            }
            const int slot = (kq >> 3) + j2;            // 0..15
            const int sw = slot ^ (r0 & 7);
            *(usvec8*)&xs[r0 * INDIM + sw * 8] = o;
        }
    }

    const int wid  = tid >> 6;
    const int lane = tid & 63;
    const int r = lane & 15;
    const int g = lane >> 4;
    const int arow = wid * 16 + r;

    // alpha-tile B fragments straight from global (L2-hot 4KB)
    bf8 wa[4];
    #pragma unroll
    for (int kk = 0; kk < 4; ++kk)
        wa[kk] = *(const bf8*)&wt_g[(size_t)(256 + r) * INDIM + kk * 32 + g * 8];

    __syncthreads();

    // A fragments (reused across all 17 col-tiles)
    bf8 a[4];
    #pragma unroll
    for (int kk = 0; kk < 4; ++kk) {
        const int sw = (kk * 4 + g) ^ (arow & 7);
        a[kk] = *(const bf8*)&xs[arow * INDIM + sw * 8];
    }

    f32x4 acc[17];
    #pragma unroll
    for (int t = 0; t < 17; ++t) acc[t] = (f32x4){0.f, 0.f, 0.f, 0.f};

    #pragma unroll
    for (int kk = 0; kk < 4; ++kk) {
        #pragma unroll
        for (int t = 0; t < 16; ++t) {
            const int n = t * 16 + r;
            const int sw = (kk * 4 + g) ^ (n & 7);
            const bf8 b = *(const bf8*)&wt[n * INDIM + sw * 8];
            acc[t] = __builtin_amdgcn_mfma_f32_16x16x32_bf16(a[kk], b, acc[t], 0, 0, 0);
        }
        acc[16] = __builtin_amdgcn_mfma_f32_16x16x32_bf16(a[kk], wa[kk], acc[16], 0, 0, 0);
    }

    // alphas: D[row=4g+ri][col=r]; r<8 -> alpha_l head r, r>=8 -> alpha_r
    #pragma unroll
    for (int ri = 0; ri < 4; ++ri) {
        const size_t node = nbase + wid * 16 + 4 * g + ri;
        if (node < NNODES) {
            if (r < 8) alpha_l[node * NH + r]       = acc[16][ri];
            else       alpha_r[node * NH + (r - 8)] = acc[16][ri];
        }
    }

    // epilogue: stage D into reused wt LDS (per-wave 8KB), then wide stores
    __syncthreads();   // all waves done reading wt
    unsigned short* st = wt + wid * 4096;   // 16 rows x 256 shorts
    #pragma unroll
    for (int t = 0; t < 16; ++t) {
        #pragma unroll
        for (int ri = 0; ri < 4; ++ri) {
            const int row = 4 * g + ri;
            st[row * 256 + ((t ^ (row & 7)) << 4) + r] = f2bf_rne(acc[t][ri]);
        }
    }
    __syncthreads();   // order LDS writes before cross-lane reads

    {
        const int li = lane & 15;
        const int t  = li >> 1;
        const int half = li & 1;
        #pragma unroll
        for (int it = 0; it < 4; ++it) {
            const int row = it * 4 + (lane >> 4);
            const size_t node = nbase + wid * 16 + row;
            const usvec8 vh = *(const usvec8*)&st[row * 256 + ((t ^ (row & 7)) << 4) + half * 8];
            const usvec8 vr = *(const usvec8*)&st[row * 256 + (((8 + t) ^ (row & 7)) << 4) + half * 8];
            if (node < NNODES) {
                *(usvec8*)&h16[node * HC + li * 8]     = vh;
                *(usvec8*)&resid16[node * HC + li * 8] = vr;
            }
        }
    }
}

// ---------------------------------------------------------------------------
// CSR row_start: two-level scan over deg
// ---------------------------------------------------------------------------
__global__ __launch_bounds__(1024) void k_scan1(const int* __restrict__ deg,
                                                int* __restrict__ row_start,
                                                int* __restrict__ partials)
{
    __shared__ int sh[1024];
    const int t = threadIdx.x;
    const int i = blockIdx.x * 1024 + t;
    const int v = (i < NNODES) ? deg[i] : 0;
    sh[t] = v;
    __syncthreads();
    #pragma unroll
    for (int off = 1; off < 1024; off <<= 1) {
        int u = (t >= off) ? sh[t - off] : 0;
        __syncthreads();
        sh[t] += u;
        __syncthreads();
    }
    if (i < NNODES) row_start[i] = sh[t] - v;
    if (t == 1023) partials[blockIdx.x] = sh[1023];
}

__global__ __launch_bounds__(128) void k_scan2(int* __restrict__ partials)
{
    __shared__ int sh[128];
    const int t = threadIdx.x;
    const int v = (t < NPART) ? partials[t] : 0;
    sh[t] = v;
    __syncthreads();
    #pragma unroll
    for (int off = 1; off < 128; off <<= 1) {
        int u = (t >= off) ? sh[t - off] : 0;
        __syncthreads();
        sh[t] += u;
        __syncthreads();
    }
    if (t < NPART) partials[t] = sh[t] - v;
    if (t == 127) partials[NPART] = sh[127];
}

__global__ __launch_bounds__(1024) void k_scan3(int* __restrict__ row_start,
                                                const int* __restrict__ partials)
{
    const int i = blockIdx.x * 1024 + threadIdx.x;
    if (i < NNODES) row_start[i] += partials[blockIdx.x];
    if (i == NNODES - 1) row_start[NNODES] = partials[NPART];
}

// ---------------------------------------------------------------------------
// k_cnt: per-(block,bucket) edge counts via LDS histogram. No global atomics.
// ---------------------------------------------------------------------------
__global__ __launch_bounds__(256) void k_cnt(const int* __restrict__ ei,
                                             int* __restrict__ cnt)
{
    __shared__ int hist[NBUCK];
    const int t = threadIdx.x;
    if (t < NBUCK) hist[t] = 0;
    __syncthreads();
    const int e0 = blockIdx.x * CHUNK;
    #pragma unroll
    for (int i = 0; i < CHUNK / 256; ++i) {
        const int e = e0 + t + i * 256;
        if (e < NEDGES) atomicAdd(&hist[ei[NEDGES + e] >> 9], 1);
    }
    __syncthreads();
    if (t < NBUCK) cnt[blockIdx.x * NBUCK + t] = hist[t];
}

// ---------------------------------------------------------------------------
// k_colscan: per bucket-column exclusive scan over blocks + bucket CSR base
//   -> cnt[blk][b] becomes the absolute write offset for (blk,b).
// ---------------------------------------------------------------------------
__global__ __launch_bounds__(512) void k_colscan(int* __restrict__ cnt,
                                                 const int* __restrict__ row_start)
{
    __shared__ int sh[512];
    const int b = blockIdx.x;
    const int t = threadIdx.x;
    const int v = (t < CBLK) ? cnt[t * NBUCK + b] : 0;
    sh[t] = v;
    __syncthreads();
    #pragma unroll
    for (int off = 1; off < 512; off <<= 1) {
        int u = (t >= off) ? sh[t - off] : 0;
        __syncthreads();
        sh[t] += u;
        __syncthreads();
    }
    if (t < CBLK) cnt[t * NBUCK + b] = sh[t] - v + row_start[b * NPB_S];
}

// ---------------------------------------------------------------------------
// k_scat1b: place edges into bucket-partitioned `pairs` at precomputed
// offsets (LDS cursors only). Writes are ~21-edge contiguous runs per bucket.
// Payload: src(17b) | dst_local(9b).
// ---------------------------------------------------------------------------
__global__ __launch_bounds__(256) void k_scat1b(const int* __restrict__ ei,
                                                const int* __restrict__ ofs,
                                                uint32_t* __restrict__ pairs)
{
    __shared__ int base[NBUCK];
    __shared__ int cur[NBUCK];
    const int t = threadIdx.x;
    if (t < NBUCK) { base[t] = ofs[blockIdx.x * NBUCK + t]; cur[t] = 0; }
    __syncthreads();
    const int e0 = blockIdx.x * CHUNK;
    #pragma unroll
    for (int i = 0; i < CHUNK / 256; ++i) {
        const int e = e0 + t + i * 256;
        if (e < NEDGES) {
            const int src = ei[e];
            const int dst = ei[NEDGES + e];
            const int b = dst >> 9;
            const int pos = base[b] + atomicAdd(&cur[b], 1);
            pairs[pos] = (uint32_t)src | ((uint32_t)(dst & 511) << 17);
        }
    }
}

// ---------------------------------------------------------------------------
// k_scat2: one block per bucket; LDS per-node cursors resolve exact CSR
// positions; all writes inside the bucket's ~33KB L2-resident window.
// ---------------------------------------------------------------------------
__global__ __launch_bounds__(512) void k_scat2(const uint32_t* __restrict__ pairs,
                                               const int* __restrict__ row_start,
                                               int* __restrict__ csr_src)
{
    __shared__ int rs[NPB_S + 1];
    __shared__ int lc[NPB_S];
    const int base = blockIdx.x * NPB_S;
    const int nmax = min(NPB_S, NNODES - base);
    const int t = threadIdx.x;
    for (int i = t; i <= nmax; i += 512) rs[i] = row_start[base + i];
    if (t < nmax) lc[t] = 0;
    __syncthreads();
    const int bs = rs[0];
    const int be = rs[nmax];
    for (int i = bs + t; i < be; i += 512) {
        const uint32_t code = pairs[i];
        const int src  = code & 0x1FFFFu;
        const int dstl = code >> 17;
        const int pos = rs[dstl] + atomicAdd(&lc[dstl], 1);
        csr_src[pos] = src;
    }
}

// ---------------------------------------------------------------------------
// k_msg: one wave per dst node, 8 edges per iteration, shuffle-free score
// mapping. lane = (sub = lane>>3 -> edge slot, li = lane&7 -> 16-channel
// block == head li). Each lane computes the score (head li) for edge sub and
// uses it directly for its own channels. Final 3-level xor-reduce over sub;
// lanes sub==0 write 16 channels (ELU + resid).
// ---------------------------------------------------------------------------
__global__ __launch_bounds__(256) void k_msg(
    const int* __restrict__ row_start,
    const int* __restrict__ csr_src,
    const float* __restrict__ alpha_l,
    const float* __restrict__ alpha_r,
    const unsigned short* __restrict__ h16,
    const unsigned short* __restrict__ resid16,
    float* __restrict__ out)
{
    const int n = blockIdx.x * 4 + (threadIdx.x >> 6);
    if (n >= NNODES) return;
    const int lane = threadIdx.x & 63;
    const int sub  = lane >> 3;     // edge slot 0..7
    const int li   = lane & 7;      // channel block / head 0..7

    const int beg = row_start[n];
    const int end = row_start[n + 1];
    const float ar = alpha_r[(size_t)n * NH + li];
    const float* __restrict__ al_li = alpha_l + li;
    const unsigned short* __restrict__ hbase = h16 + 16 * li;

    float ssum = 0.f;
    float acc[16];
    #pragma unroll
    for (int j = 0; j < 16; ++j) acc[j] = 0.f;

    for (int p = beg; p < end; p += 8) {
        const int q = p + sub;
        const bool valid = q < end;
        const int qc = valid ? q : beg;
        const int src = csr_src[qc];
        float a = al_li[(size_t)src * NH] + ar;
        a = a > 0.f ? a : LEAKY * a;
        const float w = valid ? __expf(a) : 0.f;
        ssum += w;
        const unsigned short* hrow = hbase + (size_t)src * HC;
        const uvec4 d0 = *(const uvec4*)hrow;
        const uvec4 d1 = *(const uvec4*)(hrow + 8);
        #pragma unroll
        for (int c = 0; c < 4; ++c) {
            acc[2 * c]     += w * __builtin_bit_cast(float, d0[c] << 16);
            acc[2 * c + 1] += w * __builtin_bit_cast(float, d0[c] & 0xFFFF0000u);
            acc[8 + 2 * c]     += w * __builtin_bit_cast(float, d1[c] << 16);
            acc[8 + 2 * c + 1] += w * __builtin_bit_cast(float, d1[c] & 0xFFFF0000u);
        }
    }

    // reduce across the 8 edge subgroups (lane bits 3,4,5); li preserved
    ssum += __shfl_xor(ssum, 8);
    ssum += __shfl_xor(ssum, 16);
    ssum += __shfl_xor(ssum, 32);
    #pragma unroll
    for (int j = 0; j < 16; ++j) {
        acc[j] += __shfl_xor(acc[j], 8);
        acc[j] += __shfl_xor(acc[j], 16);
        acc[j] += __shfl_xor(acc[j], 32);
    }

    if (sub == 0) {
        const float inv = 1.f / (ssum + SM_EPS);
        const unsigned short* rrow = resid16 + (size_t)n * HC + 16 * li;
        const uvec4 r0 = *(const uvec4*)rrow;
        const uvec4 r1 = *(const uvec4*)(rrow + 8);
        float res[16];
        #pragma unroll
        for (int c = 0; c < 4; ++c) {
            res[2 * c]         = __builtin_bit_cast(float, r0[c] << 16);
            res[2 * c + 1]     = __builtin_bit_cast(float, r0[c] & 0xFFFF0000u);
            res[8 + 2 * c]     = __builtin_bit_cast(float, r1[c] << 16);
            res[8 + 2 * c + 1] = __builtin_bit_cast(float, r1[c] & 0xFFFF0000u);
        }
        float* orow = out + (size_t)n * HC + 16 * li;
        #pragma unroll
        for (int v4 = 0; v4 < 4; ++v4) {
            fvec4 o;
            #pragma unroll
            for (int j = 0; j < 4; ++j) {
                float v = acc[v4 * 4 + j] * inv;
                o[j] = (v > 0.f ? v : expm1f(v)) + res[v4 * 4 + j];
            }
            *(fvec4*)&orow[v4 * 4] = o;
        }
    }
}

extern "C" void kernel_launch(void* const* d_in, const int* in_sizes, int n_in,
                              void* d_out, int out_size, void* d_ws, size_t ws_size,
                              hipStream_t stream)
{
    const float* x     = (const float*)d_in[0];
    const int*   ei    = (const int*)d_in[1];
    const float* W_lin = (const float*)d_in[2];
    const float* att_l = (const float*)d_in[3];
    const float* att_r = (const float*)d_in[4];
    const float* W_res = (const float*)d_in[5];
    float* out = (float*)d_out;

    // workspace layout
    unsigned short* wt_g    = (unsigned short*)d_ws;              // 272*128
    unsigned short* h16     = wt_g + (size_t)WROWS * INDIM;       // N*128
    unsigned short* resid16 = h16 + (size_t)NNODES * HC;          // N*128
    float* alpha_l  = (float*)(resid16 + (size_t)NNODES * HC);    // N*8
    float* alpha_r  = alpha_l + (size_t)NNODES * NH;              // N*8
    int*   deg      = (int*)(alpha_r + (size_t)NNODES * NH);      // N
    int*   row_start= deg + NNODES;                               // N+1
    int*   partials = row_start + NNODES + 1;                     // NPART+1
    int*   cnt      = partials + NPART + 1;                       // CBLK*NBUCK
    uint32_t* pairs = (uint32_t*)(cnt + CBLK * NBUCK);            // E
    int*   csr_src  = (int*)(pairs + NEDGES);                     // E

    // zero deg every launch (ws is not re-poisoned between replays)
    hipMemsetAsync(deg, 0, (size_t)NNODES * sizeof(int), stream);

    k_wt<<<17, 256, 0, stream>>>(W_lin, W_res, att_l, att_r, wt_g);
    k_gemm<<<GEMM_BLOCKS, 256, 0, stream>>>(x, wt_g, ei, h16, resid16,
                                            alpha_l, alpha_r, deg);
    k_cnt<<<CBLK, 256, 0, stream>>>(ei, cnt);
    k_scan1<<<NPART, 1024, 0, stream>>>(deg, row_start, partials);
    k_scan2<<<1, 128, 0, stream>>>(partials);
    k_scan3<<<NPART, 1024, 0, stream>>>(row_start, partials);
    k_colscan<<<NBUCK, 512, 0, stream>>>(cnt, row_start);
    k_scat1b<<<CBLK, 256, 0, stream>>>(ei, cnt, pairs);
    k_scat2<<<NBUCK, 512, 0, stream>>>(pairs, row_start, csr_src);
    k_msg<<<(NNODES + 3) / 4, 256, 0, stream>>>(row_start, csr_src, alpha_l, alpha_r,
                                                h16, resid16, out);
}

// Round 10
// 233.074 us; speedup vs baseline: 1.0146x; 1.0146x over previous
//
#include <hip/hip_runtime.h>
#include <cstdint>
#include <cstddef>

typedef __attribute__((ext_vector_type(4))) float fvec4;
typedef __attribute__((ext_vector_type(8))) short bf8;            // 8 bf16 = 4 VGPR MFMA frag
typedef __attribute__((ext_vector_type(8))) unsigned short usvec8;
typedef __attribute__((ext_vector_type(4))) unsigned int uvec4;
typedef __attribute__((ext_vector_type(4))) float f32x4;

#define NNODES 100000
#define NEDGES 1600000
#define INDIM  128
#define HC     128
#define NH     8
#define LEAKY  0.2f
#define SM_EPS 1e-16f
#define NPART  98    // ceil(100000/1024) for row_start scan
#define BM     64    // nodes per block in k_gemm
#define GEMM_BLOCKS ((NNODES + BM - 1) / BM)   // 1563
#define WROWS  272   // 256 W cols + 8 wa_l + 8 wa_r
#define NBUCK  196   // scatter buckets (512 nodes each; dst>>9)
#define NPB_S  512   // nodes per scatter bucket
#define CHUNK  4096  // edges per partition block
#define CBLK   ((NEDGES + CHUNK - 1) / CHUNK)  // 391

__device__ __forceinline__ unsigned short f2bf_rne(float f) {
    uint32_t u = __builtin_bit_cast(uint32_t, f);
    u += 0x7FFFu + ((u >> 16) & 1u);
    return (unsigned short)(u >> 16);
}
__device__ __forceinline__ float bf2f(uint32_t lo16) {
    return __builtin_bit_cast(float, lo16 << 16);
}

// ---------------------------------------------------------------------------
// k_wt: build wt_g (bf16):
//   rows 0..255:  W_lin|W_res transposed [n][k], pre-swizzled 16B slots (^= n&7)
//   rows 256..263: wa_l[k,hd]; rows 264..271: wa_r (att folded into W_lin).
// ---------------------------------------------------------------------------
__global__ __launch_bounds__(256) void k_wt(
    const float* __restrict__ W_lin,
    const float* __restrict__ W_res,
    const float* __restrict__ att_l,
    const float* __restrict__ att_r,
    unsigned short* __restrict__ wt_g)
{
    const int idx = blockIdx.x * 256 + threadIdx.x;   // 0..4351
    if (idx >= WROWS * 16) return;
    const int n  = idx >> 4;                          // 0..271
    const int k8 = idx & 15;
    usvec8 o;
    if (n < 256) {
        const float* src = (n < 128) ? W_lin : W_res;
        const int col = n & 127;
        #pragma unroll
        for (int j = 0; j < 8; ++j)
            o[j] = f2bf_rne(src[(size_t)(k8 * 8 + j) * HC + col]);
        const int sw = k8 ^ (n & 7);
        *(usvec8*)&wt_g[(size_t)n * INDIM + sw * 8] = o;
    } else {
        const int hd = (n - 256) & 7;
        const float* att = (n < 264) ? att_l : att_r;
        #pragma unroll
        for (int j = 0; j < 8; ++j) {
            const int k = k8 * 8 + j;
            float s = 0.f;
            #pragma unroll
            for (int c = 0; c < 16; ++c)
                s += W_lin[(size_t)k * HC + 16 * hd + c] * att[16 * hd + c];
            o[j] = f2bf_rne(s);
        }
        *(usvec8*)&wt_g[(size_t)n * INDIM + k8 * 8] = o;
    }
}

// ---------------------------------------------------------------------------
// k_gemm (MFMA): per block 64 nodes x 272 cols (h | resid | alphas), K=128.
// LDS: wt 64KB + xs 16KB = 80KB -> 2 blocks/CU. Fused dst-degree histogram.
// ---------------------------------------------------------------------------
__global__ __launch_bounds__(256) void k_gemm(
    const float* __restrict__ x,
    const unsigned short* __restrict__ wt_g,
    const int*   __restrict__ ei,
    unsigned short* __restrict__ h16,
    unsigned short* __restrict__ resid16,
    float* __restrict__ alpha_l,
    float* __restrict__ alpha_r,
    int* __restrict__ deg)
{
    __shared__ unsigned short wt[256 * INDIM];  // 64 KB
    __shared__ unsigned short xs[BM * INDIM];   // 16 KB

    const int tid = threadIdx.x;
    const size_t nbase = (size_t)blockIdx.x * BM;

    // fused histogram: 1563*256*4 >= 1.6M  (16 atomics/address -> short chains)
    #pragma unroll
    for (int i = 0; i < 4; ++i) {
        const int e = blockIdx.x * 256 + tid + i * (GEMM_BLOCKS * 256);
        if (e < NEDGES) atomicAdd(&deg[ei[NEDGES + e]], 1);
    }

    // stage wt rows 0..255 (linear copy of pre-swizzled bf16)
    {
        const fvec4* s = (const fvec4*)wt_g;
        fvec4* d = (fvec4*)wt;
        #pragma unroll
        for (int i = 0; i < 16; ++i) d[tid + 256 * i] = s[tid + 256 * i];
    }
    // stage xs: thread = (row r0, quarter kq); f32->bf16, swizzled store
    {
        const int r0 = tid >> 2;
        const int kq = (tid & 3) * 32;
        const bool valid = (nbase + r0) < NNODES;
        const float* xr = x + (nbase + r0) * INDIM + kq;
        #pragma unroll
        for (int j2 = 0; j2 < 4; ++j2) {
            usvec8 o;
            if (valid) {
                fvec4 p0 = *(const fvec4*)(xr + j2 * 8);
                fvec4 p1 = *(const fvec4*)(xr + j2 * 8 + 4);
                #pragma unroll
                for (int j = 0; j < 4; ++j) { o[j] = f2bf_rne(p0[j]); o[4 + j] = f2bf_rne(p1[j]); }
            } else {
                #pragma unroll
                for (int j = 0; j < 8; ++j) o[j] = 0;
            }
            const int slot = (kq >> 3) + j2;            // 0..15
            const int sw = slot ^ (r0 & 7);
            *(usvec8*)&xs[r0 * INDIM + sw * 8] = o;
        }
    }

    const int wid  = tid >> 6;
    const int lane = tid & 63;
    const int r = lane & 15;
    const int g = lane >> 4;
    const int arow = wid * 16 + r;

    // alpha-tile B fragments straight from global (L2-hot 4KB)
    bf8 wa[4];
    #pragma unroll
    for (int kk = 0; kk < 4; ++kk)
        wa[kk] = *(const bf8*)&wt_g[(size_t)(256 + r) * INDIM + kk * 32 + g * 8];

    __syncthreads();

    // A fragments (reused across all 17 col-tiles)
    bf8 a[4];
    #pragma unroll
    for (int kk = 0; kk < 4; ++kk) {
        const int sw = (kk * 4 + g) ^ (arow & 7);
        a[kk] = *(const bf8*)&xs[arow * INDIM + sw * 8];
    }

    f32x4 acc[17];
    #pragma unroll
    for (int t = 0; t < 17; ++t) acc[t] = (f32x4){0.f, 0.f, 0.f, 0.f};

    #pragma unroll
    for (int kk = 0; kk < 4; ++kk) {
        #pragma unroll
        for (int t = 0; t < 16; ++t) {
            const int n = t * 16 + r;
            const int sw = (kk * 4 + g) ^ (n & 7);
            const bf8 b = *(const bf8*)&wt[n * INDIM + sw * 8];
            acc[t] = __builtin_amdgcn_mfma_f32_16x16x32_bf16(a[kk], b, acc[t], 0, 0, 0);
        }
        acc[16] = __builtin_amdgcn_mfma_f32_16x16x32_bf16(a[kk], wa[kk], acc[16], 0, 0, 0);
    }

    // alphas: D[row=4g+ri][col=r]; r<8 -> alpha_l head r, r>=8 -> alpha_r
    #pragma unroll
    for (int ri = 0; ri < 4; ++ri) {
        const size_t node = nbase + wid * 16 + 4 * g + ri;
        if (node < NNODES) {
            if (r < 8) alpha_l[node * NH + r]       = acc[16][ri];
            else       alpha_r[node * NH + (r - 8)] = acc[16][ri];
        }
    }

    // epilogue: stage D into reused wt LDS (per-wave 8KB), then wide stores
    __syncthreads();   // all waves done reading wt
    unsigned short* st = wt + wid * 4096;   // 16 rows x 256 shorts
    #pragma unroll
    for (int t = 0; t < 16; ++t) {
        #pragma unroll
        for (int ri = 0; ri < 4; ++ri) {
            const int row = 4 * g + ri;
            st[row * 256 + ((t ^ (row & 7)) << 4) + r] = f2bf_rne(acc[t][ri]);
        }
    }
    __syncthreads();   // order LDS writes before cross-lane reads

    {
        const int li = lane & 15;
        const int t  = li >> 1;
        const int half = li & 1;
        #pragma unroll
        for (int it = 0; it < 4; ++it) {
            const int row = it * 4 + (lane >> 4);
            const size_t node = nbase + wid * 16 + row;
            const usvec8 vh = *(const usvec8*)&st[row * 256 + ((t ^ (row & 7)) << 4) + half * 8];
            const usvec8 vr = *(const usvec8*)&st[row * 256 + (((8 + t) ^ (row & 7)) << 4) + half * 8];
            if (node < NNODES) {
                *(usvec8*)&h16[node * HC + li * 8]     = vh;
                *(usvec8*)&resid16[node * HC + li * 8] = vr;
            }
        }
    }
}

// ---------------------------------------------------------------------------
// CSR row_start: two-level scan over deg
// ---------------------------------------------------------------------------
__global__ __launch_bounds__(1024) void k_scan1(const int* __restrict__ deg,
                                                int* __restrict__ row_start,
                                                int* __restrict__ partials)
{
    __shared__ int sh[1024];
    const int t = threadIdx.x;
    const int i = blockIdx.x * 1024 + t;
    const int v = (i < NNODES) ? deg[i] : 0;
    sh[t] = v;
    __syncthreads();
    #pragma unroll
    for (int off = 1; off < 1024; off <<= 1) {
        int u = (t >= off) ? sh[t - off] : 0;
        __syncthreads();
        sh[t] += u;
        __syncthreads();
    }
    if (i < NNODES) row_start[i] = sh[t] - v;
    if (t == 1023) partials[blockIdx.x] = sh[1023];
}

__global__ __launch_bounds__(128) void k_scan2(int* __restrict__ partials)
{
    __shared__ int sh[128];
    const int t = threadIdx.x;
    const int v = (t < NPART) ? partials[t] : 0;
    sh[t] = v;
    __syncthreads();
    #pragma unroll
    for (int off = 1; off < 128; off <<= 1) {
        int u = (t >= off) ? sh[t - off] : 0;
        __syncthreads();
        sh[t] += u;
        __syncthreads();
    }
    if (t < NPART) partials[t] = sh[t] - v;
    if (t == 127) partials[NPART] = sh[127];
}

__global__ __launch_bounds__(1024) void k_scan3(int* __restrict__ row_start,
                                                const int* __restrict__ partials)
{
    const int i = blockIdx.x * 1024 + threadIdx.x;
    if (i < NNODES) row_start[i] += partials[blockIdx.x];
    if (i == NNODES - 1) row_start[NNODES] = partials[NPART];
}

// ---------------------------------------------------------------------------
// k_cnt: per-(block,bucket) edge counts via LDS histogram. No global atomics.
// ---------------------------------------------------------------------------
__global__ __launch_bounds__(256) void k_cnt(const int* __restrict__ ei,
                                             int* __restrict__ cnt)
{
    __shared__ int hist[NBUCK];
    const int t = threadIdx.x;
    if (t < NBUCK) hist[t] = 0;
    __syncthreads();
    const int e0 = blockIdx.x * CHUNK;
    #pragma unroll
    for (int i = 0; i < CHUNK / 256; ++i) {
        const int e = e0 + t + i * 256;
        if (e < NEDGES) atomicAdd(&hist[ei[NEDGES + e] >> 9], 1);
    }
    __syncthreads();
    if (t < NBUCK) cnt[blockIdx.x * NBUCK + t] = hist[t];
}

// ---------------------------------------------------------------------------
// k_colscan: per bucket-column exclusive scan over blocks + bucket CSR base
//   -> cnt[blk][b] becomes the absolute write offset for (blk,b).
// ---------------------------------------------------------------------------
__global__ __launch_bounds__(512) void k_colscan(int* __restrict__ cnt,
                                                 const int* __restrict__ row_start)
{
    __shared__ int sh[512];
    const int b = blockIdx.x;
    const int t = threadIdx.x;
    const int v = (t < CBLK) ? cnt[t * NBUCK + b] : 0;
    sh[t] = v;
    __syncthreads();
    #pragma unroll
    for (int off = 1; off < 512; off <<= 1) {
        int u = (t >= off) ? sh[t - off] : 0;
        __syncthreads();
        sh[t] += u;
        __syncthreads();
    }
    if (t < CBLK) cnt[t * NBUCK + b] = sh[t] - v + row_start[b * NPB_S];
}

// ---------------------------------------------------------------------------
// k_scat1b: place edges into bucket-partitioned `pairs` at precomputed
// offsets (LDS cursors only). Writes are ~21-edge contiguous runs per bucket.
// Payload: src(17b) | dst_local(9b).
// ---------------------------------------------------------------------------
__global__ __launch_bounds__(256) void k_scat1b(const int* __restrict__ ei,
                                                const int* __restrict__ ofs,
                                                uint32_t* __restrict__ pairs)
{
    __shared__ int base[NBUCK];
    __shared__ int cur[NBUCK];
    const int t = threadIdx.x;
    if (t < NBUCK) { base[t] = ofs[blockIdx.x * NBUCK + t]; cur[t] = 0; }
    __syncthreads();
    const int e0 = blockIdx.x * CHUNK;
    #pragma unroll
    for (int i = 0; i < CHUNK / 256; ++i) {
        const int e = e0 + t + i * 256;
        if (e < NEDGES) {
            const int src = ei[e];
            const int dst = ei[NEDGES + e];
            const int b = dst >> 9;
            const int pos = base[b] + atomicAdd(&cur[b], 1);
            pairs[pos] = (uint32_t)src | ((uint32_t)(dst & 511) << 17);
        }
    }
}

// ---------------------------------------------------------------------------
// k_scat2: one block per bucket; LDS per-node cursors resolve exact CSR
// positions; all writes inside the bucket's ~33KB L2-resident window.
// ---------------------------------------------------------------------------
__global__ __launch_bounds__(512) void k_scat2(const uint32_t* __restrict__ pairs,
                                               const int* __restrict__ row_start,
                                               int* __restrict__ csr_src)
{
    __shared__ int rs[NPB_S + 1];
    __shared__ int lc[NPB_S];
    const int base = blockIdx.x * NPB_S;
    const int nmax = min(NPB_S, NNODES - base);
    const int t = threadIdx.x;
    for (int i = t; i <= nmax; i += 512) rs[i] = row_start[base + i];
    if (t < nmax) lc[t] = 0;
    __syncthreads();
    const int bs = rs[0];
    const int be = rs[nmax];
    for (int i = bs + t; i < be; i += 512) {
        const uint32_t code = pairs[i];
        const int src  = code & 0x1FFFFu;
        const int dstl = code >> 17;
        const int pos = rs[dstl] + atomicAdd(&lc[dstl], 1);
        csr_src[pos] = src;
    }
}

// ---------------------------------------------------------------------------
// k_msg: one wave per dst node, 16 edges per iteration (2 per lane) for MLP.
// lane = (sub = lane>>3 -> edge slots {p+sub, p+sub+8}, li = lane&7 ->
// 16-channel block == head li). Both edges' csr/alpha/h loads are independent
// -> 4x 16B gathers in flight per lane per iteration; typical degree-16 node
// completes in ONE gather-latency epoch. 3-level xor-reduce over sub; lanes
// sub==0 write 16 channels (ELU + resid).
// ---------------------------------------------------------------------------
__global__ __launch_bounds__(256) void k_msg(
    const int* __restrict__ row_start,
    const int* __restrict__ csr_src,
    const float* __restrict__ alpha_l,
    const float* __restrict__ alpha_r,
    const unsigned short* __restrict__ h16,
    const unsigned short* __restrict__ resid16,
    float* __restrict__ out)
{
    const int n = blockIdx.x * 4 + (threadIdx.x >> 6);
    if (n >= NNODES) return;
    const int lane = threadIdx.x & 63;
    const int sub  = lane >> 3;     // edge slot 0..7
    const int li   = lane & 7;      // channel block / head 0..7

    const int beg = row_start[n];
    const int end = row_start[n + 1];
    const float ar = alpha_r[(size_t)n * NH + li];
    const float* __restrict__ al_li = alpha_l + li;
    const unsigned short* __restrict__ hbase = h16 + 16 * li;

    float ssum = 0.f;
    float acc[16];
    #pragma unroll
    for (int j = 0; j < 16; ++j) acc[j] = 0.f;

    for (int p = beg; p < end; p += 16) {
        const int q0 = p + sub;
        const int q1 = q0 + 8;
        const bool v0 = q0 < end;
        const bool v1 = q1 < end;
        const int src0 = csr_src[v0 ? q0 : beg];
        const int src1 = csr_src[v1 ? q1 : beg];

        float a0 = al_li[(size_t)src0 * NH] + ar;
        a0 = a0 > 0.f ? a0 : LEAKY * a0;
        const float w0 = v0 ? __expf(a0) : 0.f;
        float a1 = al_li[(size_t)src1 * NH] + ar;
        a1 = a1 > 0.f ? a1 : LEAKY * a1;
        const float w1 = v1 ? __expf(a1) : 0.f;
        ssum += w0 + w1;

        const unsigned short* hrow0 = hbase + (size_t)src0 * HC;
        const unsigned short* hrow1 = hbase + (size_t)src1 * HC;
        const uvec4 d0 = *(const uvec4*)hrow0;
        const uvec4 d1 = *(const uvec4*)(hrow0 + 8);
        const uvec4 d2 = *(const uvec4*)hrow1;
        const uvec4 d3 = *(const uvec4*)(hrow1 + 8);

        #pragma unroll
        for (int c = 0; c < 4; ++c) {
            acc[2 * c]         += w0 * __builtin_bit_cast(float, d0[c] << 16);
            acc[2 * c + 1]     += w0 * __builtin_bit_cast(float, d0[c] & 0xFFFF0000u);
            acc[8 + 2 * c]     += w0 * __builtin_bit_cast(float, d1[c] << 16);
            acc[8 + 2 * c + 1] += w0 * __builtin_bit_cast(float, d1[c] & 0xFFFF0000u);
            acc[2 * c]         += w1 * __builtin_bit_cast(float, d2[c] << 16);
            acc[2 * c + 1]     += w1 * __builtin_bit_cast(float, d2[c] & 0xFFFF0000u);
            acc[8 + 2 * c]     += w1 * __builtin_bit_cast(float, d3[c] << 16);
            acc[8 + 2 * c + 1] += w1 * __builtin_bit_cast(float, d3[c] & 0xFFFF0000u);
        }
    }

    // reduce across the 8 edge subgroups (lane bits 3,4,5); li preserved
    ssum += __shfl_xor(ssum, 8);
    ssum += __shfl_xor(ssum, 16);
    ssum += __shfl_xor(ssum, 32);
    #pragma unroll
    for (int j = 0; j < 16; ++j) {
        acc[j] += __shfl_xor(acc[j], 8);
        acc[j] += __shfl_xor(acc[j], 16);
        acc[j] += __shfl_xor(acc[j], 32);
    }

    if (sub == 0) {
        const float inv = 1.f / (ssum + SM_EPS);
        const unsigned short* rrow = resid16 + (size_t)n * HC + 16 * li;
        const uvec4 r0 = *(const uvec4*)rrow;
        const uvec4 r1 = *(const uvec4*)(rrow + 8);
        float res[16];
        #pragma unroll
        for (int c = 0; c < 4; ++c) {
            res[2 * c]         = __builtin_bit_cast(float, r0[c] << 16);
            res[2 * c + 1]     = __builtin_bit_cast(float, r0[c] & 0xFFFF0000u);
            res[8 + 2 * c]     = __builtin_bit_cast(float, r1[c] << 16);
            res[8 + 2 * c + 1] = __builtin_bit_cast(float, r1[c] & 0xFFFF0000u);
        }
        float* orow = out + (size_t)n * HC + 16 * li;
        #pragma unroll
        for (int v4 = 0; v4 < 4; ++v4) {
            fvec4 o;
            #pragma unroll
            for (int j = 0; j < 4; ++j) {
                float v = acc[v4 * 4 + j] * inv;
                o[j] = (v > 0.f ? v : expm1f(v)) + res[v4 * 4 + j];
            }
            *(fvec4*)&orow[v4 * 4] = o;
        }
    }
}

extern "C" void kernel_launch(void* const* d_in, const int* in_sizes, int n_in,
                              void* d_out, int out_size, void* d_ws, size_t ws_size,
                              hipStream_t stream)
{
    const float* x     = (const float*)d_in[0];
    const int*   ei    = (const int*)d_in[1];
    const float* W_lin = (const float*)d_in[2];
    const float* att_l = (const float*)d_in[3];
    const float* att_r = (const float*)d_in[4];
    const float* W_res = (const float*)d_in[5];
    float* out = (float*)d_out;

    // workspace layout
    unsigned short* wt_g    = (unsigned short*)d_ws;              // 272*128
    unsigned short* h16     = wt_g + (size_t)WROWS * INDIM;       // N*128
    unsigned short* resid16 = h16 + (size_t)NNODES * HC;          // N*128
    float* alpha_l  = (float*)(resid16 + (size_t)NNODES * HC);    // N*8
    float* alpha_r  = alpha_l + (size_t)NNODES * NH;              // N*8
    int*   deg      = (int*)(alpha_r + (size_t)NNODES * NH);      // N
    int*   row_start= deg + NNODES;                               // N+1
    int*   partials = row_start + NNODES + 1;                     // NPART+1
    int*   cnt      = partials + NPART + 1;                       // CBLK*NBUCK
    uint32_t* pairs = (uint32_t*)(cnt + CBLK * NBUCK);            // E
    int*   csr_src  = (int*)(pairs + NEDGES);                     // E

    // zero deg every launch (ws is not re-poisoned between replays)
    hipMemsetAsync(deg, 0, (size_t)NNODES * sizeof(int), stream);

    k_wt<<<17, 256, 0, stream>>>(W_lin, W_res, att_l, att_r, wt_g);
    k_gemm<<<GEMM_BLOCKS, 256, 0, stream>>>(x, wt_g, ei, h16, resid16,
                                            alpha_l, alpha_r, deg);
    k_cnt<<<CBLK, 256, 0, stream>>>(ei, cnt);
    k_scan1<<<NPART, 1024, 0, stream>>>(deg, row_start, partials);
    k_scan2<<<1, 128, 0, stream>>>(partials);
    k_scan3<<<NPART, 1024, 0, stream>>>(row_start, partials);
    k_colscan<<<NBUCK, 512, 0, stream>>>(cnt, row_start);
    k_scat1b<<<CBLK, 256, 0, stream>>>(ei, cnt, pairs);
    k_scat2<<<NBUCK, 512, 0, stream>>>(pairs, row_start, csr_src);
    k_msg<<<(NNODES + 3) / 4, 256, 0, stream>>>(row_start, csr_src, alpha_l, alpha_r,
                                                h16, resid16, out);
}